// Round 4
// baseline (275.021 us; speedup 1.0000x reference)
//
#include <hip/hip_runtime.h>
#include <hip/hip_bf16.h>
#include <cstdint>
#include <cstddef>

typedef __hip_bfloat16 bf16;
using short8 = __attribute__((ext_vector_type(8))) short;
using f32x4  = __attribute__((ext_vector_type(4))) float;

static constexpr int   kNC    = 1026;   // n_fft + 2 (real S_ri cols)
static constexpr int   kKS    = 1152;   // padded S_ri cols (18*64)
static constexpr float kTwoPi = 6.283185307179586f;

#define GLDS(g, l) __builtin_amdgcn_global_load_lds(                       \
    (const __attribute__((address_space(1))) uint32_t*)(g),                \
    (__attribute__((address_space(3))) uint32_t*)(l), 16, 0, 0)

#define BAR()   { __builtin_amdgcn_sched_barrier(0); __builtin_amdgcn_s_barrier(); }
#define LGKM0() { asm volatile("s_waitcnt lgkmcnt(0)" ::: "memory"); __builtin_amdgcn_sched_barrier(0); }
#define LGKM8() { asm volatile("s_waitcnt lgkmcnt(8)" ::: "memory"); __builtin_amdgcn_sched_barrier(0); }
#define VM4()   { asm volatile("s_waitcnt vmcnt(4)" ::: "memory"); __builtin_amdgcn_sched_barrier(0); }
#define VM0()   { asm volatile("s_waitcnt vmcnt(0)" ::: "memory"); __builtin_amdgcn_sched_barrier(0); }

#define MMA(ACC) do {                                                          \
    __builtin_amdgcn_s_setprio(1);                                             \
    _Pragma("unroll") for (int fm = 0; fm < 4; ++fm)                           \
      _Pragma("unroll") for (int fn = 0; fn < 2; ++fn)                         \
        _Pragma("unroll") for (int ks = 0; ks < 2; ++ks)                       \
          ACC[fm][fn] = __builtin_amdgcn_mfma_f32_16x16x32_bf16(               \
              af[fm][ks], bq[fn][ks], ACC[fm][fn], 0, 0, 0);                   \
    __builtin_amdgcn_s_setprio(0); } while (0)

// ---------------------------------------------------------------- prep: x -> bf16
__global__ void cvt_x_k(const float* __restrict__ x, bf16* __restrict__ xb) {
    size_t i = ((size_t)blockIdx.x * 256 + threadIdx.x) * 8;
    float4 a = *(const float4*)(x + i);
    float4 c = *(const float4*)(x + i + 4);
    union { bf16 h[8]; uint4 u; } o;
    o.h[0] = __float2bfloat16(a.x); o.h[1] = __float2bfloat16(a.y);
    o.h[2] = __float2bfloat16(a.z); o.h[3] = __float2bfloat16(a.w);
    o.h[4] = __float2bfloat16(c.x); o.h[5] = __float2bfloat16(c.y);
    o.h[6] = __float2bfloat16(c.z); o.h[7] = __float2bfloat16(c.w);
    *(uint4*)(xb + i) = o.u;
}

// ------------------------------------------- prep: W -> Wr [1280][512] interleaved
__global__ void prep_w_k(const float* __restrict__ W, const float* __restrict__ b,
                         bf16* __restrict__ Wr, float* __restrict__ br) {
    int j = blockIdx.x;
    int col = -1;
    if (j < 1024)      col = (j & 1) ? 513 + (j >> 1) : (j >> 1);
    else if (j == 1024) col = 512;
    else if (j == 1025) col = 1025;
    for (int k = threadIdx.x; k < 512; k += 256) {
        float v = (col >= 0) ? W[(size_t)k * 1026 + col] : 0.0f;
        Wr[(size_t)j * 512 + k] = __float2bfloat16(v);
    }
    if (threadIdx.x == 0) br[j] = (col >= 0) ? b[col] : 0.0f;
}

// --------------------- prep: windowed irfft matrix Mw [1024 rows n][1152 cols kk]
__global__ void prep_m_k(bf16* __restrict__ Mw, float* __restrict__ w2) {
    int nrow = blockIdx.x;
    float wn = 0.5f - 0.5f * cosf(kTwoPi * (float)nrow / 1023.0f);  // numpy hanning
    for (int kk = threadIdx.x; kk < 1152; kk += 256) {
        float v = 0.0f;
        if (kk < 1026) {
            int k = kk >> 1;
            int mm = (k * nrow) & 1023;
            float ang = kTwoPi * (float)mm * (1.0f / 1024.0f);
            float alpha = (k == 0 || k == 512) ? 1.0f : 2.0f;
            float tw = (kk & 1) ? -sinf(ang) : cosf(ang);
            v = alpha * (1.0f / 1024.0f) * wn * tw;
        }
        Mw[(size_t)nrow * 1152 + kk] = __float2bfloat16(v);
    }
    if (threadIdx.x == 0) w2[nrow] = wn * wn;
}

// ---------------------------------------------- 256x256 8-phase bf16 GEMM (m201-style)
// C = A(MxK) * B^T (B stored [n][k]); BK=64, 2 K-tiles per iteration, 8 phases.
// 8 waves (wr=w>>2 in M, wc=w&3 in N); per phase one block-C quadrant (Mq,Nq):
// wave computes rows Mq*128+wr*64..+63, cols Nq*128+wc*32..+31 over K=64 (16 MFMA).
// LDS: 2 bufs x 4 halves (A.h0,A.h1,B.h0,B.h1) x [128][64] bf16, XOR-swizzled 16B slots.
// Stage schedule ph1..ph8: b1.Ah1, b1.Bh0, b0.Ah0, b0.Bh1, b0.Ah1, b0.Bh0, b1.Ah0, b1.Bh1
// (tiles t1,t1,t2,t2,t2,t2,t3,t3). vmcnt(4) at ph4/ph8 only; 4 loads always in flight.
template<int K, int LDO, int EPI, int MT>
__global__ __launch_bounds__(512, 2)
void gemm8p_k(const bf16* __restrict__ A, const bf16* __restrict__ B,
              const float* __restrict__ bias, bf16* __restrict__ O)
{
    extern __shared__ __align__(16) bf16 lds[];   // [2][4][8192]
    constexpr int NT  = K / 64;                   // even
    constexpr int NIT = NT / 2;

    const int tid  = threadIdx.x;
    const int w    = tid >> 6;
    const int lane = tid & 63;
    const int wr = w >> 2, wc = w & 3;

    const int nwg  = gridDim.x;
    const int orig = blockIdx.x;
    const int bid  = (orig & 7) * (nwg >> 3) + (orig >> 3);   // XCD-contiguous
    const int mt = bid % MT;
    const int nt = bid / MT;
    const int row0 = mt * 256;
    const int col0 = nt * 256;

    const int srow  = lane >> 3;
    const int sslot = (lane & 7) ^ srow;          // pre-swizzled global 16B slot

    // stage one half-tile (128 rows x 64 cols) of tile t into buf:
    // half 0/1 = A rows +0/+128 ; half 2/3 = B rows(cols) +0/+128
    auto stage = [&](int t, int buf, int half) {
        const bf16* src = (half < 2)
            ? A + (size_t)(row0 + half * 128) * K
            : B + (size_t)(col0 + (half - 2) * 128) * K;
        bf16* dst = lds + buf * 32768 + half * 8192;
        #pragma unroll
        for (int l = 0; l < 2; ++l) {
            const int g = w * 2 + l;              // 8-row group
            GLDS(src + (size_t)(g * 8 + srow) * K + (size_t)t * 64 + sslot * 8,
                 dst + g * 512 + lane * 8);
        }
    };

    short8 af[4][2], bq[2][2];
    auto ldaf = [&](int buf, int Mq) {
        const bf16* base = lds + buf * 32768 + Mq * 8192;
        #pragma unroll
        for (int fm = 0; fm < 4; ++fm)
            #pragma unroll
            for (int ks = 0; ks < 2; ++ks) {
                const int r = wr * 64 + fm * 16 + (lane & 15);
                const int s = ks * 4 + (lane >> 4);
                af[fm][ks] = *(const short8*)(base + r * 64 + ((s ^ (r & 7)) << 3));
            }
    };
    auto ldbq = [&](int buf, int Nq) {
        const bf16* base = lds + buf * 32768 + (2 + Nq) * 8192;
        #pragma unroll
        for (int fn = 0; fn < 2; ++fn)
            #pragma unroll
            for (int ks = 0; ks < 2; ++ks) {
                const int r = wc * 32 + fn * 16 + (lane & 15);
                const int s = ks * 4 + (lane >> 4);
                bq[fn][ks] = *(const short8*)(base + r * 64 + ((s ^ (r & 7)) << 3));
            }
    };

    f32x4 acc00[4][2] = {}, acc01[4][2] = {}, acc10[4][2] = {}, acc11[4][2] = {};

    // prologue: tile0 -> buf0 (4 halves), tile1 A.h0 + B.h1 -> buf1
    stage(0, 0, 0); stage(0, 0, 1); stage(0, 0, 2); stage(0, 0, 3);
    if (NT > 1) { stage(1, 1, 0); stage(1, 1, 3); }
    VM4(); BAR();

    for (int i = 0; i < NIT; ++i) {
        const int t1 = 2 * i + 1;
        const int t2 = (2 * i + 2 < NT) ? 2 * i + 2 : NT - 1;   // clamped prefetch
        const int t3 = (2 * i + 3 < NT) ? 2 * i + 3 : NT - 1;
        // ---- tile 2i from buf0 ----
        ldaf(0, 0); ldbq(0, 0); stage(t1, 1, 1);                 // ph1 (0,0)
        LGKM8(); BAR(); LGKM0(); MMA(acc00); BAR();
        ldbq(0, 1); stage(t1, 1, 2);                             // ph2 (0,1)
        BAR(); LGKM0(); MMA(acc01); BAR();
        ldaf(0, 1); stage(t2, 0, 0);                             // ph3 (1,1)
        BAR(); LGKM0(); MMA(acc11); BAR();
        ldbq(0, 0); stage(t2, 0, 3); VM4();                      // ph4 (1,0) — buf1 ready
        BAR(); LGKM0(); MMA(acc10); BAR();
        // ---- tile 2i+1 from buf1 ----
        ldaf(1, 0); ldbq(1, 0); stage(t2, 0, 1);                 // ph5 (0,0)
        LGKM8(); BAR(); LGKM0(); MMA(acc00); BAR();
        ldbq(1, 1); stage(t2, 0, 2);                             // ph6 (0,1)
        BAR(); LGKM0(); MMA(acc01); BAR();
        ldaf(1, 1); stage(t3, 1, 0);                             // ph7 (1,1)
        BAR(); LGKM0(); MMA(acc11); BAR();
        ldbq(1, 0); stage(t3, 1, 3); VM4();                      // ph8 (1,0) — buf0 ready
        BAR(); LGKM0(); MMA(acc10); BAR();
    }
    VM0();   // drain clamped garbage prefetches before kernel end

    // ------------------------------------------------------------------ epilogue
    #define EPIW(ACC, MQ, NQ)                                                   \
        _Pragma("unroll") for (int fm = 0; fm < 4; ++fm)                        \
        _Pragma("unroll") for (int fn = 0; fn < 2; ++fn) {                      \
            const int n = col0 + NQ * 128 + wc * 32 + fn * 16 + (lane & 15);    \
            _Pragma("unroll") for (int r = 0; r < 4; ++r) {                     \
                const int m = row0 + MQ * 128 + wr * 64 + fm * 16 + (lane >> 4) * 4 + r; \
                float v = ACC[fm][fn][r];                                       \
                if constexpr (EPI == 1) {                                       \
                    v += bias[n];                                               \
                    float vo = __shfl_xor(v, 1);                                \
                    float res = (n & 1) ? fminf(__expf(vo), 100.0f) * __sinf(v) \
                                        : fminf(__expf(v), 100.0f) * __cosf(vo);\
                    if (n < kNC)                                                \
                        O[(size_t)m * LDO + n] = __float2bfloat16(res);         \
                    else if (n < kKS)                                           \
                        O[(size_t)m * LDO + n] = __float2bfloat16(0.0f);        \
                } else {                                                        \
                    O[(size_t)m * LDO + n] = __float2bfloat16(v);               \
                }                                                               \
            }                                                                   \
        }
    EPIW(acc00, 0, 0) EPIW(acc01, 0, 1) EPIW(acc10, 1, 0) EPIW(acc11, 1, 1)
    #undef EPIW
}

// ------------------------------------------------------------- overlap-add gather
__global__ void ola_k(const bf16* __restrict__ frames, const float* __restrict__ w2g,
                      float* __restrict__ out) {
    __shared__ float w2[1024];
    for (int i = threadIdx.x; i < 1024; i += 256) w2[i] = w2g[i];
    __syncthreads();
    int o  = blockIdx.x * 256 + threadIdx.x;
    int b  = o >> 19;
    int oo = o & 524287;
    int s  = oo + 384;
    int tmax = s >> 8;
    float sum = 0.0f, env = 0.0f;
    #pragma unroll
    for (int jj = 0; jj < 4; ++jj) {
        int t = tmax - jj;
        if (t >= 0 && t < 2048) {
            int n = s - (t << 8);
            sum += __bfloat162float(frames[(((size_t)b * 2048 + t) << 10) + n]);
            env += w2[n];
        }
    }
    out[o] = sum / (env + 1e-11f);
}

// ---------------------------------------------------------------------- launcher
extern "C" void kernel_launch(void* const* d_in, const int* in_sizes, int n_in,
                              void* d_out, int out_size, void* d_ws, size_t ws_size,
                              hipStream_t stream)
{
    const float* x = (const float*)d_in[0];
    const float* W = (const float*)d_in[1];
    const float* b = (const float*)d_in[2];
    float* out = (float*)d_out;

    char* ws = (char*)d_ws;
    size_t off = 0;
    auto alloc = [&](size_t bytes) { char* p = ws + off; off += (bytes + 255) & ~255ull; return p; };

    bf16*  Mw  = (bf16*) alloc(1024ull * 1152 * 2);
    float* w2  = (float*)alloc(1024 * 4);
    float* br  = (float*)alloc(1280 * 4);
    bf16*  Sri = (bf16*) alloc(32768ull * 1152 * 2);   // (Re,Im) interleaved, K-padded
    char*  regC = alloc(67108864ull);
    bf16*  xb     = (bf16*)regC;
    bf16*  Wr     = (bf16*)(regC + 33554432ull);       // [1280][512]
    bf16*  frames = (bf16*)regC;                       // aliases xb+Wr after GEMM1

    hipFuncSetAttribute(reinterpret_cast<const void*>(gemm8p_k<512, 1152, 1, 128>),
                        hipFuncAttributeMaxDynamicSharedMemorySize, 131072);
    hipFuncSetAttribute(reinterpret_cast<const void*>(gemm8p_k<1152, 1024, 0, 128>),
                        hipFuncAttributeMaxDynamicSharedMemorySize, 131072);

    cvt_x_k <<<dim3(8192), dim3(256), 0, stream>>>(x, xb);
    prep_w_k<<<dim3(1280), dim3(256), 0, stream>>>(W, b, Wr, br);
    prep_m_k<<<dim3(1024), dim3(256), 0, stream>>>(Mw, w2);
    // GEMM1: (32768 x 1280) = xb @ Wr^T, fused exp/cos/sin -> Sri (LDO 1152)
    gemm8p_k<512, 1152, 1, 128><<<dim3(640), dim3(512), 131072, stream>>>(xb, Wr, br, Sri);
    // GEMM2: (32768 x 1024) = Sri @ Mw^T -> windowed frames
    gemm8p_k<1152, 1024, 0, 128><<<dim3(512), dim3(512), 131072, stream>>>(Sri, Mw, nullptr, frames);
    ola_k   <<<dim3(32768), dim3(256), 0, stream>>>(frames, w2, out);
    (void)in_sizes; (void)n_in; (void)out_size; (void)ws_size;
}